// Round 9
// baseline (174.567 us; speedup 1.0000x reference)
//
#include <hip/hip_runtime.h>

// ---------------------------------------------------------------------------
// GMMConv forward — int8-gather, DMA-staged-A edition (hardened resubmit of
// R8: container died twice before pytest; the only never-exercised construct
// was a PER-LANE LDS dest pointer to global_load_lds — now wave-uniform).
//  0) convert_W (R5): row remap so gemm lane (wave,l16,ni) owns
//     (f=wave*16+l16, k=ni) -> register epilogue packs one nfq dword/lane;
//     16B k-granule XOR swizzle for LDS bank spread.
//  1) gemm_fused v7b: R7 counters (MfmaUtil 4.5%, VALUBusy 9.9%, HBM 9.7% —
//     ALL pipes idle) prove exposed-latency. A is DMA'd fp32 straight to
//     LDS via global_load_lds: per (pass p, wave w), row = p*4+w, LDS dest
//     = Asb + row*1024 (WAVE-UNIFORM; HW adds lane*16), global src =
//     feat[row] + ((lane*16) ^ ((row&7)<<5)) — inverse-swizzled source,
//     linear dest (rule 21; same pattern as the proven B path). 20
//     fire-and-forget DMAs/wave, zero VGPR round-trips; cvt4h moves to
//     fragment read. 80 KB LDS, 2 blocks/CU. K-loop/epilogue unchanged
//     from R5 (barrier-free, wave-private Bs, register epilogue).
//     Math bit-identical -> absmax 0.625.
//  2) edge_aggregate v4 (unchanged, passed R3/R5/R7): schedule-invariant
//     ~41 us across three schedules -> L3-equilibrium-pinned; not touched.
// ---------------------------------------------------------------------------

typedef _Float16 f16;
typedef __attribute__((ext_vector_type(4))) _Float16 f16x4;
typedef __attribute__((ext_vector_type(8))) _Float16 f16x8;
typedef __attribute__((ext_vector_type(4))) float f32x4;

__device__ inline f16x4 cvt4h(float4 v) {
    f16x4 h;
    h.x = (f16)v.x; h.y = (f16)v.y; h.z = (f16)v.z; h.w = (f16)v.w;
    return h;
}

__device__ inline int dot4_i8(int a, int b) {
#if __has_builtin(__builtin_amdgcn_sdot4)
    return __builtin_amdgcn_sdot4(a, b, 0, false);
#else
    return (int)(char)(a)       * (int)(char)(b)
         + (int)(char)(a >> 8)  * (int)(char)(b >> 8)
         + (int)(char)(a >> 16) * (int)(char)(b >> 16)
         + (int)(char)(a >> 24) * (int)(char)(b >> 24);
#endif
}

// W_fc fp32 [256][256] -> Wp f16 [256][256].
// Placed row jp holds logical W-row (k*64 + f) with k=(jp>>4)&3,
// f=(jp>>6)*16 + (jp&15)  ->  gemm lane (wave,l16,ni) owns (f=wave*16+l16,
// k=ni), i.e. the 4 bytes of output dword f. 16B k-granules XOR-swizzled
// within each 64B ki-slice (granule ^= jp&3) for LDS bank spread.
__global__ __launch_bounds__(256) void convert_W(
    const float* __restrict__ W, f16* __restrict__ Wp)
{
    const int gid = blockIdx.x * 256 + threadIdx.x;   // 64 blocks -> 16384
    const int jp = gid >> 6, k4 = gid & 63;
    const int wrow = ((jp >> 4) & 3) * 64 + ((jp >> 6) << 4) + (jp & 15);
    const int k4s = k4 ^ ((jp & 3) << 1);             // B bank swizzle
    reinterpret_cast<f16x4*>(Wp)[jp * 64 + k4s] =
        cvt4h(reinterpret_cast<const float4*>(W)[wrow * 64 + k4]);
}

// nfq[m] dword f: byte k = i8 quant of node_feat[m][k][f]
// sc[m][g] = groupAbsmax / 127^2 for feature group g = f>>4
__global__ __launch_bounds__(256, 2) void gemm_fused(
    const float* __restrict__ feat,   // fp32 [M][256]
    const f16* __restrict__ Wp,       // f16 [256][256] permuted+swizzled
    char* __restrict__ nfq,           // i8 [M][256]
    float* __restrict__ sc,           // f32 [M][4]
    int M)
{
    // As fp32 64KB (64 rows x 1024B, LDS[o] = global[o ^ ((row&7)<<5)])
    // + Bs f16 16KB (wave-private quarters)
    __shared__ char smem[65536 + 16384];              // 80 KB -> 2 blocks/CU
    char* Asb = smem;
    char* Bsb = smem + 65536;
    const int t    = threadIdx.x;
    const int lane = t & 63;
    const int wave = t >> 6;
    const int bm   = blockIdx.x * 64;
    const int l16  = lane & 15;
    const int quad = lane >> 4;
    const int wn   = wave * 64;

    size_t bsrc[4];
#pragma unroll
    for (int j = 0; j < 4; ++j)
        bsrc[j] = (size_t)(wave * 64 + j * 16 + (lane >> 2)) * 256 + (lane & 3) * 8;

    typedef __attribute__((address_space(3))) void lds_t;
    typedef const __attribute__((address_space(1))) void gm_t;

    // B DMA for ki=0 (wave-private quarter of Bs; uniform LDS dest)
#pragma unroll
    for (int j = 0; j < 4; ++j)
        __builtin_amdgcn_global_load_lds((gm_t*)(Wp + bsrc[j]),
            (lds_t*)(Bsb + (wave * 4 + j) * 1024), 16, 0, 0);

    // A DMA: 16 passes; pass p, wave w stages row = p*4+w (1024 B).
    // LDS dest is WAVE-UNIFORM (Asb + row*1024); HW adds lane*16. The
    // granule that lands at +lane*16 is global byte (lane*16) ^ key —
    // inverse-swizzled per-lane GLOBAL source (rule 21, proven B pattern).
#pragma unroll
    for (int p = 0; p < 16; ++p) {
        const int row = p * 4 + wave;            // wave-uniform 0..63
        const int key = (row & 7) << 5;
        const int gcol = ((lane << 4) ^ key) >> 2;   // fp32 index in row
        const float* gsrc =
            feat + (size_t)min(bm + row, M - 1) * 256 + gcol;
        __builtin_amdgcn_global_load_lds((gm_t*)gsrc,
            (lds_t*)(Asb + row * 1024), 16, 0, 0);
    }

    f32x4 acc[4][4];
#pragma unroll
    for (int mi = 0; mi < 4; ++mi)
#pragma unroll
        for (int ni = 0; ni < 4; ++ni)
            acc[mi][ni] = (f32x4){0.f, 0.f, 0.f, 0.f};

    asm volatile("s_waitcnt vmcnt(0)" ::: "memory");  // this wave's DMAs done
    __syncthreads();                                  // all waves' DMAs done

    const int bxor = (l16 & 3) << 4;
    const int arow = (l16 & 7) << 5;                  // A swizzle key (row&7)

    // K-loop: no block barriers (R5 discipline). Wave-private Bs; next B
    // DMA issued only after this tile's ds_reads completed (lgkmcnt(0)).
#pragma unroll
    for (int ki = 0; ki < 8; ++ki) {
        __builtin_amdgcn_sched_barrier(0);
        asm volatile("s_waitcnt vmcnt(0)" ::: "memory");   // Bs(ki) landed
        __builtin_amdgcn_sched_barrier(0);

        float4 a0[4], a1[4];
        f16x8 bfr[4];
#pragma unroll
        for (int mi = 0; mi < 4; ++mi) {
            const char* ap = Asb + (mi * 16 + l16) * 1024 +
                             ((ki * 128 + quad * 32) ^ arow);
            a0[mi] = *reinterpret_cast<const float4*>(ap);
            a1[mi] = *reinterpret_cast<const float4*>(ap + 16);
        }
#pragma unroll
        for (int ni = 0; ni < 4; ++ni)
            bfr[ni] = *reinterpret_cast<const f16x8*>(
                Bsb + (wn + ni * 16 + l16) * 64 + ((quad << 4) ^ bxor));

        __builtin_amdgcn_sched_barrier(0);
        asm volatile("s_waitcnt lgkmcnt(0)" ::: "memory"); // reads done
        __builtin_amdgcn_sched_barrier(0);

        if (ki < 7) {
            const int k0 = (ki + 1) * 32;
#pragma unroll
            for (int j = 0; j < 4; ++j)
                __builtin_amdgcn_global_load_lds((gm_t*)(Wp + bsrc[j] + k0),
                    (lds_t*)(Bsb + (wave * 4 + j) * 1024), 16, 0, 0);
        }

        f16x8 af[4];
#pragma unroll
        for (int mi = 0; mi < 4; ++mi) {
            const f16x4 h0 = cvt4h(a0[mi]);
            const f16x4 h1 = cvt4h(a1[mi]);
            af[mi] = (f16x8){h0.x, h0.y, h0.z, h0.w, h1.x, h1.y, h1.z, h1.w};
        }
#pragma unroll
        for (int mi = 0; mi < 4; ++mi)
#pragma unroll
            for (int ni = 0; ni < 4; ++ni)
                acc[mi][ni] = __builtin_amdgcn_mfma_f32_16x16x32_f16(
                    af[mi], bfr[ni], acc[mi][ni], 0, 0, 0);
    }

    // Register epilogue (R5): no LDS, no barriers.
    // C/D layout: col = lane&15, row = quad*4 + reg  [m89; dtype-independent]
    // This lane's 4 ni-values = bytes k=0..3 of output dword f = wave*16+l16.
#pragma unroll
    for (int mi = 0; mi < 4; ++mi) {
#pragma unroll
        for (int r = 0; r < 4; ++r) {
            float am = 0.f;
#pragma unroll
            for (int ni = 0; ni < 4; ++ni)
                am = fmaxf(am, fabsf(acc[mi][ni][r]));
            am = fmaxf(am, __shfl_xor(am, 1));   // reduce over l16 (same quad)
            am = fmaxf(am, __shfl_xor(am, 2));
            am = fmaxf(am, __shfl_xor(am, 4));
            am = fmaxf(am, __shfl_xor(am, 8));
            const float sinv = am > 0.f ? 127.f / am : 0.f;
            unsigned pk = 0;
#pragma unroll
            for (int k = 0; k < 4; ++k) {
                const int b = (int)__builtin_rintf(acc[mi][k][r] * sinv);
                pk |= (unsigned)(b & 255) << (8 * k);
            }
            const int rl  = mi * 16 + quad * 4 + r;
            const int row = bm + rl;
            if (row < M) {
                reinterpret_cast<unsigned*>(nfq + (size_t)row * 256)
                    [wave * 16 + l16] = pk;
                if (l16 == 0) sc[row * 4 + wave] = am * (1.f / 16129.f);
            }
        }
    }
}

// Two dst nodes per wave, cross-node pipelined. lane = (eg = l>>4 : edge slot
// in group-of-4, fo = l&15 : feature quad). v4: gaussian deduplicated — each
// lane computes ONE kernel (kk = l>>4) of edge fo and the 4 bytes are packed
// across the kk-lanes with 2 shfl_xor|or.
__global__ __launch_bounds__(256) void edge_aggregate(
    const int* __restrict__ rowptr,
    const int* __restrict__ colind,
    const float* __restrict__ pseudo,   // [E][2]
    const char* __restrict__ nfq,       // i8 [N][256] dword f, byte k
    const float* __restrict__ sc,       // f32 [N][4] group scales
    const float* __restrict__ mu,
    const float* __restrict__ inv_sigma,
    const float* __restrict__ bias,
    float* __restrict__ out,            // [N][64]
    int N)
{
    const int lane = threadIdx.x & 63;
    const int wid  = blockIdx.x * 4 + (threadIdx.x >> 6);
    const int na   = wid * 2;
    if (na >= N) return;                // wave-uniform; no barriers below
    const int nb   = na + 1;
    const bool hb  = nb < N;

    const int fo   = lane & 15;         // feature quad: f = 4*fo + r
    const int eg   = lane >> 4;         // edge slot within a group of 4
    const int qoff = fo << 4;           // byte offset into a 256 B nfq row
    const int goff = fo >> 2;           // scale group = f>>4

    // per-lane kernel constants: this lane owns kernel kk = lane>>4
    const int kk = lane >> 4;
    const float mx = mu[2 * kk], my = mu[2 * kk + 1];
    const float sa = inv_sigma[2 * kk], sb = inv_sigma[2 * kk + 1];
    const float C  = -0.5f * 1.4426950408889634f;     // fold log2(e)
    const float cx = C * sa * sa, cy = C * sb * sb;
    const int   sh = kk * 8;

    // packed 4-kernel gaussians for the 16-edge chunk at ec: lane computes
    // kernel kk of edge fo, then OR-combines bytes across the 4 kk-lanes.
    auto gpack = [&](int ec, int e0, int e1) -> int {
        const int exm = ec + fo;
        const bool gv = exm < e1;
        const int safe = (e1 > e0) ? (e1 - 1) : 0;
        const int ex  = gv ? exm : safe;
        const float2 p = *reinterpret_cast<const float2*>(pseudo + 2 * (size_t)ex);
        const float dx = p.x - mx, dy = p.y - my;
        const float g = exp2f(fmaf(dy * dy, cy, dx * dx * cx));
        int b = gv ? (((int)(g * 127.f + 0.5f)) << sh) : 0;
        b |= __shfl_xor(b, 16);
        b |= __shfl_xor(b, 32);
        return b;
    };

    const int ea0 = rowptr[na];
    const int ea1 = rowptr[na + 1];
    const int eb0 = ea1;
    const int eb1 = hb ? rowptr[nb + 1] : ea1;

    // ---- stage BOTH nodes' first chunks up front (independent loads)
    const int safea = (ea1 > ea0) ? (ea1 - 1) : 0;
    int cfo_a = colind[min(ea0 + fo, safea)];
    int cfo_b = 0, gpk_b = 0;
    if (hb) {
        const int safeb = (eb1 > eb0) ? (eb1 - 1) : 0;
        cfo_b = colind[min(eb0 + fo, safeb)];
        gpk_b = gpack(eb0, eb0, eb1);
    }
    int gpk_a = gpack(ea0, ea0, ea1);

    // ---- node a
    float a0 = 0.f, a1 = 0.f, a2 = 0.f, a3 = 0.f;
    {
        int gpk = gpk_a, cfo = cfo_a;
        for (int ec = ea0; ec < ea1; ec += 16) {
            int4  q[4];
            float s[4];
            int   gq[4];
#pragma unroll
            for (int gi = 0; gi < 4; ++gi) {
                const int c = __shfl(cfo, gi * 4 + eg);
                q[gi]  = *reinterpret_cast<const int4*>(
                             nfq + ((size_t)c << 8) + qoff);
                s[gi]  = sc[c * 4 + goff];
                gq[gi] = __shfl(gpk, gi * 4 + eg);
            }
            const int ecn = ec + 16;
            int gpk_n = 0, cfo_n = cfo;
            if (ecn < ea1) {
                cfo_n = colind[min(ecn + fo, ea1 - 1)];
                gpk_n = gpack(ecn, ea0, ea1);
            }
#pragma unroll
            for (int gi = 0; gi < 4; ++gi) {
                a0 = fmaf(s[gi], (float)dot4_i8(q[gi].x, gq[gi]), a0);
                a1 = fmaf(s[gi], (float)dot4_i8(q[gi].y, gq[gi]), a1);
                a2 = fmaf(s[gi], (float)dot4_i8(q[gi].z, gq[gi]), a2);
                a3 = fmaf(s[gi], (float)dot4_i8(q[gi].w, gq[gi]), a3);
            }
            gpk = gpk_n; cfo = cfo_n;
        }
    }
    a0 += __shfl_xor(a0, 16); a0 += __shfl_xor(a0, 32);
    a1 += __shfl_xor(a1, 16); a1 += __shfl_xor(a1, 32);
    a2 += __shfl_xor(a2, 16); a2 += __shfl_xor(a2, 32);
    a3 += __shfl_xor(a3, 16); a3 += __shfl_xor(a3, 32);
    if (lane < 16) {
        const float4 b4 = reinterpret_cast<const float4*>(bias)[fo];
        float4 o;
        o.x = a0 + b4.x; o.y = a1 + b4.y; o.z = a2 + b4.z; o.w = a3 + b4.w;
        reinterpret_cast<float4*>(out + ((size_t)na << 6))[fo] = o;
    }

    // ---- node b (first chunk's colind/pseudo already resident)
    if (!hb) return;
    float b0 = 0.f, b1 = 0.f, b2 = 0.f, b3 = 0.f;
    {
        int gpk = gpk_b, cfo = cfo_b;
        for (int ec = eb0; ec < eb1; ec += 16) {
            int4  q[4];
            float s[4];
            int   gq[4];
#pragma unroll
            for (int gi = 0; gi < 4; ++gi) {
                const int c = __shfl(cfo, gi * 4 + eg);
                q[gi]  = *reinterpret_cast<const int4*>(
                             nfq + ((size_t)c << 8) + qoff);
                s[gi]  = sc[c * 4 + goff];
                gq[gi] = __shfl(gpk, gi * 4 + eg);
            }
            const int ecn = ec + 16;
            int gpk_n = 0, cfo_n = cfo;
            if (ecn < eb1) {
                cfo_n = colind[min(ecn + fo, eb1 - 1)];
                gpk_n = gpack(ecn, eb0, eb1);
            }
#pragma unroll
            for (int gi = 0; gi < 4; ++gi) {
                b0 = fmaf(s[gi], (float)dot4_i8(q[gi].x, gq[gi]), b0);
                b1 = fmaf(s[gi], (float)dot4_i8(q[gi].y, gq[gi]), b1);
                b2 = fmaf(s[gi], (float)dot4_i8(q[gi].z, gq[gi]), b2);
                b3 = fmaf(s[gi], (float)dot4_i8(q[gi].w, gq[gi]), b3);
            }
            gpk = gpk_n; cfo = cfo_n;
        }
    }
    b0 += __shfl_xor(b0, 16); b0 += __shfl_xor(b0, 32);
    b1 += __shfl_xor(b1, 16); b1 += __shfl_xor(b1, 32);
    b2 += __shfl_xor(b2, 16); b2 += __shfl_xor(b2, 32);
    b3 += __shfl_xor(b3, 16); b3 += __shfl_xor(b3, 32);
    if (lane < 16) {
        const float4 b4 = reinterpret_cast<const float4*>(bias)[fo];
        float4 o;
        o.x = b0 + b4.x; o.y = b1 + b4.y; o.z = b2 + b4.z; o.w = b3 + b4.w;
        reinterpret_cast<float4*>(out + ((size_t)nb << 6))[fo] = o;
    }
}

extern "C" void kernel_launch(void* const* d_in, const int* in_sizes, int n_in,
                              void* d_out, int out_size, void* d_ws, size_t ws_size,
                              hipStream_t stream)
{
    const int*   rowptr    = (const int*)d_in[0];
    const int*   colind    = (const int*)d_in[1];
    // d_in[2] colptr, d_in[3] rowind, d_in[4] permute: inert in forward math
    const float* feat      = (const float*)d_in[5];
    const float* pseudo    = (const float*)d_in[6];
    const float* W_fc      = (const float*)d_in[7];
    const float* mu        = (const float*)d_in[8];
    const float* inv_sigma = (const float*)d_in[9];
    const float* bias      = (const float*)d_in[10];
    float* out = (float*)d_out;

    const int N = in_sizes[0] - 1;        // 50000
    char*  nfq = (char*)d_ws;             // i8 [N][256] = 12.8 MB
    float* sc  = (float*)(nfq + (size_t)N * 256);  // f32 [N][4] = 0.8 MB
    f16*   Wp  = (f16*)d_out;             // 128 KB overlay; edge rewrites
                                          // all of d_out afterwards

    hipLaunchKernelGGL(convert_W, dim3(64), dim3(256), 0, stream, W_fc, Wp);

    hipLaunchKernelGGL(gemm_fused, dim3((N + 63) / 64), dim3(256), 0, stream,
                       feat, Wp, nfq, sc, N);

    // 4 waves/block, 2 nodes/wave -> 8 nodes/block
    hipLaunchKernelGGL(edge_aggregate, dim3((N + 7) / 8), dim3(256), 0, stream,
                       rowptr, colind, pseudo, nfq, sc, mu, inv_sigma, bias, out, N);
}

// Round 10
// 161.898 us; speedup vs baseline: 1.0783x; 1.0783x over previous
//
#include <hip/hip_runtime.h>

// ---------------------------------------------------------------------------
// GMMConv forward — int8-gather, register-epilogue edition (R5 REVERT —
// best verified state: 163.1 us, absmax 0.625).
//  R9 post-mortem: DMA-staged-fp32-A regressed (42-48 us gemm, bank
//  conflicts 600K->8.2M: 1024B row stride + (row&7)<<5 key varies only
//  bank bits 3-4 -> 4-way b128 conflicts; 80KB LDS -> 2 blocks/CU).
//  Session ledger at this point:
//   - 2x268MB harness poison fills: 83 us @ 81% HBM peak (immovable).
//   - edge_aggregate: ~41.5 us, invariant across 3 schedules (latency-width,
//     cross-node overlap, VALU-dedup); VALU-issue-seconds conserved ->
//     random-gather/L3-fill equilibrium.
//   - gemm_fused: ~37 us, invariant across 6 structures (barriers, dbuf,
//     epilogue, occupancy, generation, DMA-A); all pipes >84% idle.
//   - convert_W: ~2 us.
//  0) convert_W: row remap so gemm lane (wave,l16,ni) owns (f=wave*16+l16,
//     k=ni) -> register epilogue packs one nfq dword/lane; 16B k-granule
//     XOR swizzle for LDS bank spread.
//  1) gemm_fused v3: As f16 32KB swizzled + single wave-private Bs 16KB,
//     barrier-free K-loop (counted waits), register epilogue.
//  2) edge_aggregate v4: 2 nodes/wave cross-node pipelined, dedup'd
//     gaussian (1 exp/lane + 2 shfl_xor pack), int4 gathers, sdot4.
//  Precision: absmax 0.625 (threshold 2.19).
// ---------------------------------------------------------------------------

typedef _Float16 f16;
typedef __attribute__((ext_vector_type(4))) _Float16 f16x4;
typedef __attribute__((ext_vector_type(8))) _Float16 f16x8;
typedef __attribute__((ext_vector_type(4))) float f32x4;

__device__ inline f16x4 cvt4h(float4 v) {
    f16x4 h;
    h.x = (f16)v.x; h.y = (f16)v.y; h.z = (f16)v.z; h.w = (f16)v.w;
    return h;
}

__device__ inline int dot4_i8(int a, int b) {
#if __has_builtin(__builtin_amdgcn_sdot4)
    return __builtin_amdgcn_sdot4(a, b, 0, false);
#else
    return (int)(char)(a)       * (int)(char)(b)
         + (int)(char)(a >> 8)  * (int)(char)(b >> 8)
         + (int)(char)(a >> 16) * (int)(char)(b >> 16)
         + (int)(char)(a >> 24) * (int)(char)(b >> 24);
#endif
}

// W_fc fp32 [256][256] -> Wp f16 [256][256].
// Placed row jp holds logical W-row (k*64 + f) with k=(jp>>4)&3,
// f=(jp>>6)*16 + (jp&15)  ->  gemm lane (wave,l16,ni) owns (f=wave*16+l16,
// k=ni), i.e. the 4 bytes of output dword f. 16B k-granules XOR-swizzled
// within each 64B ki-slice (granule ^= jp&3) for LDS bank spread.
__global__ __launch_bounds__(256) void convert_W(
    const float* __restrict__ W, f16* __restrict__ Wp)
{
    const int gid = blockIdx.x * 256 + threadIdx.x;   // 64 blocks -> 16384
    const int jp = gid >> 6, k4 = gid & 63;
    const int wrow = ((jp >> 4) & 3) * 64 + ((jp >> 6) << 4) + (jp & 15);
    const int k4s = k4 ^ ((jp & 3) << 1);             // B bank swizzle
    reinterpret_cast<f16x4*>(Wp)[jp * 64 + k4s] =
        cvt4h(reinterpret_cast<const float4*>(W)[wrow * 64 + k4]);
}

// nfq[m] dword f: byte k = i8 quant of node_feat[m][k][f]
// sc[m][g] = groupAbsmax / 127^2 for feature group g = f>>4
__global__ __launch_bounds__(256) void gemm_fused(
    const float* __restrict__ feat,   // fp32 [M][256]
    const f16* __restrict__ Wp,       // f16 [256][256] permuted+swizzled
    char* __restrict__ nfq,           // i8 [M][256]
    float* __restrict__ sc,           // f32 [M][4]
    int M)
{
    // As 32KB swizzled + single Bs 16KB (wave-private quarters) = 48 KB
    __shared__ char smem[32768 + 16384];
    char* Asb = smem;
    char* Bsb = smem + 32768;
    const int t    = threadIdx.x;
    const int lane = t & 63;
    const int wave = t >> 6;
    const int bm   = blockIdx.x * 64;
    const int l16  = lane & 15;
    const int quad = lane >> 4;
    const int wn   = wave * 64;

    size_t bsrc[4];
#pragma unroll
    for (int j = 0; j < 4; ++j)
        bsrc[j] = (size_t)(wave * 64 + j * 16 + (lane >> 2)) * 256 + (lane & 3) * 8;

    typedef __attribute__((address_space(3))) void lds_t;
    typedef const __attribute__((address_space(1))) void gm_t;

    // kick off B DMA for ki=0, then stage A (fp32->f16, swizzled) while it
    // flies; the A-loads' in-order vmcnt retirement also retires these DMAs
    // before the prologue barrier.
#pragma unroll
    for (int j = 0; j < 4; ++j)
        __builtin_amdgcn_global_load_lds((gm_t*)(Wp + bsrc[j]),
            (lds_t*)(Bsb + (wave * 4 + j) * 1024), 16, 0, 0);

#pragma unroll
    for (int it = 0; it < 8; ++it) {
        const int flat = it * 2048 + t * 8;
        const int row  = flat >> 8;              // 0..63
        const int koff = flat & 255;             // multiple of 8
        const float* src = feat + (size_t)min(bm + row, M - 1) * 256 + koff;
        const float4 a0 = *reinterpret_cast<const float4*>(src);
        const float4 a1 = *reinterpret_cast<const float4*>(src + 4);
        char* dst = Asb + row * 512 + ((koff * 2) ^ ((row & 7) << 4));
        *reinterpret_cast<f16x4*>(dst)     = cvt4h(a0);
        *reinterpret_cast<f16x4*>(dst + 8) = cvt4h(a1);
    }

    f32x4 acc[4][4];
#pragma unroll
    for (int mi = 0; mi < 4; ++mi)
#pragma unroll
        for (int ni = 0; ni < 4; ++ni)
            acc[mi][ni] = (f32x4){0.f, 0.f, 0.f, 0.f};

    __syncthreads();                  // As ready (Bs(0) already retired)

    const int axor = (l16 & 7) << 4;
    const int bxor = (l16 & 3) << 4;

    // K-loop: no block barriers. Single wave-private Bs region; the next
    // tile's DMA is issued only after this tile's ds_reads have completed
    // (lgkmcnt(0) + sched_barrier), so write-before-read cannot occur.
#pragma unroll
    for (int ki = 0; ki < 8; ++ki) {
        __builtin_amdgcn_sched_barrier(0);
        asm volatile("s_waitcnt vmcnt(0)" ::: "memory");   // Bs(ki) landed
        __builtin_amdgcn_sched_barrier(0);

        f16x8 af[4], bfr[4];
#pragma unroll
        for (int mi = 0; mi < 4; ++mi)
            af[mi] = *reinterpret_cast<const f16x8*>(
                Asb + (mi * 16 + l16) * 512 + ((ki * 64 + quad * 16) ^ axor));
#pragma unroll
        for (int ni = 0; ni < 4; ++ni)
            bfr[ni] = *reinterpret_cast<const f16x8*>(
                Bsb + (wn + ni * 16 + l16) * 64 + ((quad << 4) ^ bxor));

        __builtin_amdgcn_sched_barrier(0);
        asm volatile("s_waitcnt lgkmcnt(0)" ::: "memory"); // reads done -> Bs free
        __builtin_amdgcn_sched_barrier(0);

        if (ki < 7) {
            const int k0 = (ki + 1) * 32;
#pragma unroll
            for (int j = 0; j < 4; ++j)
                __builtin_amdgcn_global_load_lds((gm_t*)(Wp + bsrc[j] + k0),
                    (lds_t*)(Bsb + (wave * 4 + j) * 1024), 16, 0, 0);
        }

#pragma unroll
        for (int mi = 0; mi < 4; ++mi)
#pragma unroll
            for (int ni = 0; ni < 4; ++ni)
                acc[mi][ni] = __builtin_amdgcn_mfma_f32_16x16x32_f16(
                    af[mi], bfr[ni], acc[mi][ni], 0, 0, 0);
    }

    // Register epilogue: no LDS, no barriers.
    // C/D layout: col = lane&15, row = quad*4 + reg  [m89; dtype-independent]
    // This lane's 4 ni-values = bytes k=0..3 of output dword f = wave*16+l16.
#pragma unroll
    for (int mi = 0; mi < 4; ++mi) {
#pragma unroll
        for (int r = 0; r < 4; ++r) {
            float am = 0.f;
#pragma unroll
            for (int ni = 0; ni < 4; ++ni)
                am = fmaxf(am, fabsf(acc[mi][ni][r]));
            am = fmaxf(am, __shfl_xor(am, 1));   // reduce over l16 (same quad)
            am = fmaxf(am, __shfl_xor(am, 2));
            am = fmaxf(am, __shfl_xor(am, 4));
            am = fmaxf(am, __shfl_xor(am, 8));
            const float sinv = am > 0.f ? 127.f / am : 0.f;
            unsigned pk = 0;
#pragma unroll
            for (int k = 0; k < 4; ++k) {
                const int b = (int)__builtin_rintf(acc[mi][k][r] * sinv);
                pk |= (unsigned)(b & 255) << (8 * k);
            }
            const int rl  = mi * 16 + quad * 4 + r;
            const int row = bm + rl;
            if (row < M) {
                reinterpret_cast<unsigned*>(nfq + (size_t)row * 256)
                    [wave * 16 + l16] = pk;
                if (l16 == 0) sc[row * 4 + wave] = am * (1.f / 16129.f);
            }
        }
    }
}

// Two dst nodes per wave, cross-node pipelined. lane = (eg = l>>4 : edge slot
// in group-of-4, fo = l&15 : feature quad). v4: gaussian deduplicated — each
// lane computes ONE kernel (kk = l>>4) of edge fo and the 4 bytes are packed
// across the kk-lanes with 2 shfl_xor|or.
__global__ __launch_bounds__(256) void edge_aggregate(
    const int* __restrict__ rowptr,
    const int* __restrict__ colind,
    const float* __restrict__ pseudo,   // [E][2]
    const char* __restrict__ nfq,       // i8 [N][256] dword f, byte k
    const float* __restrict__ sc,       // f32 [N][4] group scales
    const float* __restrict__ mu,
    const float* __restrict__ inv_sigma,
    const float* __restrict__ bias,
    float* __restrict__ out,            // [N][64]
    int N)
{
    const int lane = threadIdx.x & 63;
    const int wid  = blockIdx.x * 4 + (threadIdx.x >> 6);
    const int na   = wid * 2;
    if (na >= N) return;                // wave-uniform; no barriers below
    const int nb   = na + 1;
    const bool hb  = nb < N;

    const int fo   = lane & 15;         // feature quad: f = 4*fo + r
    const int eg   = lane >> 4;         // edge slot within a group of 4
    const int qoff = fo << 4;           // byte offset into a 256 B nfq row
    const int goff = fo >> 2;           // scale group = f>>4

    // per-lane kernel constants: this lane owns kernel kk = lane>>4
    const int kk = lane >> 4;
    const float mx = mu[2 * kk], my = mu[2 * kk + 1];
    const float sa = inv_sigma[2 * kk], sb = inv_sigma[2 * kk + 1];
    const float C  = -0.5f * 1.4426950408889634f;     // fold log2(e)
    const float cx = C * sa * sa, cy = C * sb * sb;
    const int   sh = kk * 8;

    // packed 4-kernel gaussians for the 16-edge chunk at ec: lane computes
    // kernel kk of edge fo, then OR-combines bytes across the 4 kk-lanes.
    auto gpack = [&](int ec, int e0, int e1) -> int {
        const int exm = ec + fo;
        const bool gv = exm < e1;
        const int safe = (e1 > e0) ? (e1 - 1) : 0;
        const int ex  = gv ? exm : safe;
        const float2 p = *reinterpret_cast<const float2*>(pseudo + 2 * (size_t)ex);
        const float dx = p.x - mx, dy = p.y - my;
        const float g = exp2f(fmaf(dy * dy, cy, dx * dx * cx));
        int b = gv ? (((int)(g * 127.f + 0.5f)) << sh) : 0;
        b |= __shfl_xor(b, 16);
        b |= __shfl_xor(b, 32);
        return b;
    };

    const int ea0 = rowptr[na];
    const int ea1 = rowptr[na + 1];
    const int eb0 = ea1;
    const int eb1 = hb ? rowptr[nb + 1] : ea1;

    // ---- stage BOTH nodes' first chunks up front (independent loads)
    const int safea = (ea1 > ea0) ? (ea1 - 1) : 0;
    int cfo_a = colind[min(ea0 + fo, safea)];
    int cfo_b = 0, gpk_b = 0;
    if (hb) {
        const int safeb = (eb1 > eb0) ? (eb1 - 1) : 0;
        cfo_b = colind[min(eb0 + fo, safeb)];
        gpk_b = gpack(eb0, eb0, eb1);
    }
    int gpk_a = gpack(ea0, ea0, ea1);

    // ---- node a
    float a0 = 0.f, a1 = 0.f, a2 = 0.f, a3 = 0.f;
    {
        int gpk = gpk_a, cfo = cfo_a;
        for (int ec = ea0; ec < ea1; ec += 16) {
            int4  q[4];
            float s[4];
            int   gq[4];
#pragma unroll
            for (int gi = 0; gi < 4; ++gi) {
                const int c = __shfl(cfo, gi * 4 + eg);
                q[gi]  = *reinterpret_cast<const int4*>(
                             nfq + ((size_t)c << 8) + qoff);
                s[gi]  = sc[c * 4 + goff];
                gq[gi] = __shfl(gpk, gi * 4 + eg);
            }
            const int ecn = ec + 16;
            int gpk_n = 0, cfo_n = cfo;
            if (ecn < ea1) {
                cfo_n = colind[min(ecn + fo, ea1 - 1)];
                gpk_n = gpack(ecn, ea0, ea1);
            }
#pragma unroll
            for (int gi = 0; gi < 4; ++gi) {
                a0 = fmaf(s[gi], (float)dot4_i8(q[gi].x, gq[gi]), a0);
                a1 = fmaf(s[gi], (float)dot4_i8(q[gi].y, gq[gi]), a1);
                a2 = fmaf(s[gi], (float)dot4_i8(q[gi].z, gq[gi]), a2);
                a3 = fmaf(s[gi], (float)dot4_i8(q[gi].w, gq[gi]), a3);
            }
            gpk = gpk_n; cfo = cfo_n;
        }
    }
    a0 += __shfl_xor(a0, 16); a0 += __shfl_xor(a0, 32);
    a1 += __shfl_xor(a1, 16); a1 += __shfl_xor(a1, 32);
    a2 += __shfl_xor(a2, 16); a2 += __shfl_xor(a2, 32);
    a3 += __shfl_xor(a3, 16); a3 += __shfl_xor(a3, 32);
    if (lane < 16) {
        const float4 b4 = reinterpret_cast<const float4*>(bias)[fo];
        float4 o;
        o.x = a0 + b4.x; o.y = a1 + b4.y; o.z = a2 + b4.z; o.w = a3 + b4.w;
        reinterpret_cast<float4*>(out + ((size_t)na << 6))[fo] = o;
    }

    // ---- node b (first chunk's colind/pseudo already resident)
    if (!hb) return;
    float b0 = 0.f, b1 = 0.f, b2 = 0.f, b3 = 0.f;
    {
        int gpk = gpk_b, cfo = cfo_b;
        for (int ec = eb0; ec < eb1; ec += 16) {
            int4  q[4];
            float s[4];
            int   gq[4];
#pragma unroll
            for (int gi = 0; gi < 4; ++gi) {
                const int c = __shfl(cfo, gi * 4 + eg);
                q[gi]  = *reinterpret_cast<const int4*>(
                             nfq + ((size_t)c << 8) + qoff);
                s[gi]  = sc[c * 4 + goff];
                gq[gi] = __shfl(gpk, gi * 4 + eg);
            }
            const int ecn = ec + 16;
            int gpk_n = 0, cfo_n = cfo;
            if (ecn < eb1) {
                cfo_n = colind[min(ecn + fo, eb1 - 1)];
                gpk_n = gpack(ecn, eb0, eb1);
            }
#pragma unroll
            for (int gi = 0; gi < 4; ++gi) {
                b0 = fmaf(s[gi], (float)dot4_i8(q[gi].x, gq[gi]), b0);
                b1 = fmaf(s[gi], (float)dot4_i8(q[gi].y, gq[gi]), b1);
                b2 = fmaf(s[gi], (float)dot4_i8(q[gi].z, gq[gi]), b2);
                b3 = fmaf(s[gi], (float)dot4_i8(q[gi].w, gq[gi]), b3);
            }
            gpk = gpk_n; cfo = cfo_n;
        }
    }
    b0 += __shfl_xor(b0, 16); b0 += __shfl_xor(b0, 32);
    b1 += __shfl_xor(b1, 16); b1 += __shfl_xor(b1, 32);
    b2 += __shfl_xor(b2, 16); b2 += __shfl_xor(b2, 32);
    b3 += __shfl_xor(b3, 16); b3 += __shfl_xor(b3, 32);
    if (lane < 16) {
        const float4 b4 = reinterpret_cast<const float4*>(bias)[fo];
        float4 o;
        o.x = b0 + b4.x; o.y = b1 + b4.y; o.z = b2 + b4.z; o.w = b3 + b4.w;
        reinterpret_cast<float4*>(out + ((size_t)nb << 6))[fo] = o;
    }
}

extern "C" void kernel_launch(void* const* d_in, const int* in_sizes, int n_in,
                              void* d_out, int out_size, void* d_ws, size_t ws_size,
                              hipStream_t stream)
{
    const int*   rowptr    = (const int*)d_in[0];
    const int*   colind    = (const int*)d_in[1];
    // d_in[2] colptr, d_in[3] rowind, d_in[4] permute: inert in forward math
    const float* feat      = (const float*)d_in[5];
    const float* pseudo    = (const float*)d_in[6];
    const float* W_fc      = (const float*)d_in[7];
    const float* mu        = (const float*)d_in[8];
    const float* inv_sigma = (const float*)d_in[9];
    const float* bias      = (const float*)d_in[10];
    float* out = (float*)d_out;

    const int N = in_sizes[0] - 1;        // 50000
    char*  nfq = (char*)d_ws;             // i8 [N][256] = 12.8 MB
    float* sc  = (float*)(nfq + (size_t)N * 256);  // f32 [N][4] = 0.8 MB
    f16*   Wp  = (f16*)d_out;             // 128 KB overlay; edge rewrites
                                          // all of d_out afterwards

    hipLaunchKernelGGL(convert_W, dim3(64), dim3(256), 0, stream, W_fc, Wp);

    hipLaunchKernelGGL(gemm_fused, dim3((N + 63) / 64), dim3(256), 0, stream,
                       feat, Wp, nfq, sc, N);

    // 4 waves/block, 2 nodes/wave -> 8 nodes/block
    hipLaunchKernelGGL(edge_aggregate, dim3((N + 7) / 8), dim3(256), 0, stream,
                       rowptr, colind, pseudo, nfq, sc, mu, inv_sigma, bias, out, N);
}